// Round 4
// baseline (568.630 us; speedup 1.0000x reference)
//
#include <hip/hip_runtime.h>

#define BH 64            // B*H heads
#define SEQ 8192
#define DK 128
#define DV 128
#define CS 64            // s-rows per LDS stage
#define LR 72            // LDS row pitch in f16 (144 B: 16B-aligned rows)

typedef _Float16 f16;
typedef _Float16 f16x4 __attribute__((ext_vector_type(4)));
typedef _Float16 f16x8 __attribute__((ext_vector_type(8)));
typedef float f32x4 __attribute__((ext_vector_type(4)));

// Phase 1: per (head, s-chunk) block of 512 threads (8 waves). Each wave owns 32
// of the 256 output cols (0..127 = phi^T V, 128..255 = phi^T phi).
// v4: dwordx4 global loads (4x fewer VMEM requests -- R1/R3 were request-rate
// limited at ~52 cyc/instr). Thread (rt,ft) owns a 4-row x 4-feat tile,
// transposed in-register. LDS XOR-swizzle u' = u ^ (ft&14) keeps both the
// f16x4 transposed writes (4-phase floor) and f16x8 MFMA reads (8-phase floor)
// conflict-free. Same 32-VGPR prefetch budget as R1 (no R2-style spill).
template <int NC, bool PARTIAL>
__global__ __launch_bounds__(512, 4) void delta_phase1(
    const float* __restrict__ Kg, const float* __restrict__ Vg,
    float* __restrict__ dstP,   // PARTIAL: ws partial base ; atomic: newM
    float* __restrict__ dstG,   // PARTIAL: unused         ; atomic: Gws
    float* __restrict__ newZ)
{
  __shared__ f16 phi_lds[DK * LR];  // [feat][s] transposed, f16, XOR-swizzled
  __shared__ f16 v_lds[DV * LR];

  constexpr int SC  = SEQ / NC;   // s-rows per block
  constexpr int NST = SC / CS;    // stages

  const int chunk = blockIdx.x;
  const int bh    = blockIdx.y;
  const int tid   = threadIdx.x;
  const int wave  = tid >> 6;    // 0..7
  const int lane  = tid & 63;
  const int chi   = lane >> 5;   // 0/1
  const int f15_  = lane & 15;
  const int quad  = lane >> 4;   // 0..3

  const int ft = tid & 31;       // feat group: feats ft*4 .. ft*4+3
  const int rt = tid >> 5;       // row group (u-unit): rows rt*4 .. rt*4+3
  const int swu = (rt ^ (ft & 14)) << 2;  // swizzled s-offset (f16 units)

  const float* Kh = Kg + ((size_t)bh * SEQ + (size_t)chunk * SC) * DK
                       + (size_t)(rt * 4) * DK + ft * 4;
  const float* Vh = Vg + ((size_t)bh * SEQ + (size_t)chunk * SC) * DV
                       + (size_t)(rt * 4) * DV + ft * 4;

  f32x4 acc[8][2];   // 8 row-tiles x 2 col-tiles of 16x16 (wave owns 32 cols)
#pragma unroll
  for (int r = 0; r < 8; ++r)
#pragma unroll
    for (int c = 0; c < 2; ++c)
      acc[r][c] = (f32x4){0.f, 0.f, 0.f, 0.f};

  float zacc[4] = {0.f, 0.f, 0.f, 0.f};  // colsum partials, feat = ft*4 + ff

  f32x4 ka[4], va[4];   // prefetch: 4 rows x 4 feats per tensor (32 VGPR total)
#define LOAD_STAGE(ST)                                              \
  {                                                                 \
    const float* kp_ = Kh + (size_t)(ST) * CS * DK;                 \
    const float* vp_ = Vh + (size_t)(ST) * CS * DV;                 \
    _Pragma("unroll")                                               \
    for (int j = 0; j < 4; ++j) {                                   \
      ka[j] = *(const f32x4*)(kp_ + (size_t)j * DK);                \
      va[j] = *(const f32x4*)(vp_ + (size_t)j * DV);                \
    }                                                               \
  }

  // lgkm-only barrier: orders LDS write->read / read->overwrite without
  // draining outstanding global loads (correctness proven in R2/R3 runs).
#define BAR()                                                       \
  {                                                                 \
    asm volatile("s_waitcnt lgkmcnt(0)" ::: "memory");              \
    __builtin_amdgcn_s_barrier();                                   \
  }

  LOAD_STAGE(0);

  for (int st = 0; st < NST; ++st) {
    // Convert + in-register transpose + swizzled LDS store (consumes prefetch).
#pragma unroll
    for (int ff = 0; ff < 4; ++ff) {
      const int feat = ft * 4 + ff;
      float p0, p1, p2, p3;
      {
        const float a0 = ka[0][ff], a1 = ka[1][ff];
        const float a2 = ka[2][ff], a3 = ka[3][ff];
        p0 = a0 > 0.f ? a0 + 1.f : __expf(a0);  // elu(x)+1
        p1 = a1 > 0.f ? a1 + 1.f : __expf(a1);
        p2 = a2 > 0.f ? a2 + 1.f : __expf(a2);
        p3 = a3 > 0.f ? a3 + 1.f : __expf(a3);
      }
      zacc[ff] += (p0 + p1) + (p2 + p3);
      const int idx = feat * LR + swu;
      *(f16x4*)&phi_lds[idx] = (f16x4){(f16)p0, (f16)p1, (f16)p2, (f16)p3};
      *(f16x4*)&v_lds[idx] =
          (f16x4){(f16)va[0][ff], (f16)va[1][ff], (f16)va[2][ff], (f16)va[3][ff]};
    }

    // Refill prefetch regs for stage st+1 BEFORE the barrier: loads in flight
    // across barrier + MFMA + barrier. (WAR on ka/va safe: in-order issue
    // reads VALU operands before the new loads write back.)
    if (st + 1 < NST) LOAD_STAGE(st + 1);

    BAR();   // LDS writes visible; no vmcnt drain

    // Compute: 2 K-steps of 32 over s. Reads apply the matching XOR swizzle.
    const f16* bsrc  = (wave < 4) ? v_lds : phi_lds;
    const int  cbase = (wave < 4) ? wave * 32 : wave * 32 - 128;
    __builtin_amdgcn_s_setprio(1);
#pragma unroll
    for (int ss = 0; ss < 2; ++ss) {
      const int u0 = ss * 8 + quad * 2;
      f16x8 bfr[2];
#pragma unroll
      for (int c = 0; c < 2; ++c) {
        const int fB = cbase + c * 16 + f15_;
        bfr[c] = *(const f16x8*)&bsrc[fB * LR + ((u0 ^ ((fB >> 2) & 14)) << 2)];
      }
#pragma unroll
      for (int r = 0; r < 8; ++r) {
        const int fA = r * 16 + f15_;
        const f16x8 afr =
            *(const f16x8*)&phi_lds[fA * LR + ((u0 ^ ((fA >> 2) & 14)) << 2)];
        acc[r][0] = __builtin_amdgcn_mfma_f32_16x16x32_f16(afr, bfr[0], acc[r][0], 0, 0, 0);
        acc[r][1] = __builtin_amdgcn_mfma_f32_16x16x32_f16(afr, bfr[1], acc[r][1], 0, 0, 0);
      }
    }
    __builtin_amdgcn_s_setprio(0);

    BAR();   // LDS reads done before next stage's convert overwrites
  }
#undef LOAD_STAGE
#undef BAR

  // Epilogue: C/D layout col=lane&15, row=quad*4+reg
  if (PARTIAL) {
    const size_t pb = (size_t)(bh * NC + chunk) * (128 * 256);
#pragma unroll
    for (int r = 0; r < 8; ++r)
#pragma unroll
      for (int c = 0; c < 2; ++c) {
        const int col = wave * 32 + c * 16 + f15_;
#pragma unroll
        for (int q = 0; q < 4; ++q) {
          const int row = r * 16 + quad * 4 + q;
          dstP[pb + (size_t)row * 256 + col] = acc[r][c][q];
        }
      }
  } else {
    const size_t mb = (size_t)bh * DK * DV;
#pragma unroll
    for (int r = 0; r < 8; ++r)
#pragma unroll
      for (int c = 0; c < 2; ++c) {
        const int col = wave * 32 + c * 16 + f15_;
#pragma unroll
        for (int q = 0; q < 4; ++q) {
          const int row = r * 16 + quad * 4 + q;
          const float v = acc[r][c][q];
          if (col < DV)
            atomicAdd(&dstP[mb + (size_t)row * DV + col], v);
          else
            atomicAdd(&dstG[mb + (size_t)row * DK + (col - DV)], v);
        }
      }
  }
  // z: lanes l and l+32 hold the same feats (rt pair) -> shfl reduce, then one
  // atomic per feat per wave (8 waves cover all 16 rt groups).
#pragma unroll
  for (int ff = 0; ff < 4; ++ff) {
    float v = zacc[ff];
    v += __shfl_xor(v, 32, 64);
    if (chi == 0) atomicAdd(&newZ[bh * DK + (tid & 31) * 4 + ff], v);
  }
}

// Reduce per-chunk partials: newM(cols<128) = M + sum, Gred(cols>=128) = sum.
// v4: f32x4 loads/stores (4x fewer VMEM requests).
__global__ __launch_bounds__(256) void delta_reduce(
    const float* __restrict__ Pp, const float* __restrict__ Mg,
    float* __restrict__ newM, float* __restrict__ Gred, int NC)
{
  const int ct  = blockIdx.x;       // 0..7 -> 32-col tile
  const int bh  = blockIdx.y;
  const int tid = threadIdx.x;
  const int col = ct * 32 + (tid & 7) * 4;   // 4-col group
  const int rb  = tid >> 3;         // 0..31

  f32x4 acc[4];
#pragma unroll
  for (int i = 0; i < 4; ++i) acc[i] = (f32x4){0.f, 0.f, 0.f, 0.f};

  const float* base = Pp + (size_t)(bh * NC) * 32768;
  for (int ch = 0; ch < NC; ++ch) {
    const float* p = base + (size_t)ch * 32768;
#pragma unroll
    for (int i = 0; i < 4; ++i)
      acc[i] += *(const f32x4*)&p[(size_t)(rb + 32 * i) * 256 + col];
  }
  if (col < 128) {
#pragma unroll
    for (int i = 0; i < 4; ++i) {
      const int row = rb + 32 * i;
      const f32x4 m = *(const f32x4*)&Mg[(size_t)bh * 16384 + (size_t)row * 128 + col];
      *(f32x4*)&newM[(size_t)bh * 16384 + (size_t)row * 128 + col] = m + acc[i];
    }
  } else {
#pragma unroll
    for (int i = 0; i < 4; ++i) {
      const int row = rb + 32 * i;
      *(f32x4*)&Gred[(size_t)bh * 16384 + (size_t)row * 128 + (col - 128)] = acc[i];
    }
  }
}

// newM -= G * M (per head, fp32).
__global__ __launch_bounds__(256) void delta_gm(
    const float* __restrict__ Mg, const float* __restrict__ G, float* __restrict__ newM)
{
  __shared__ float Gs[64 * 129];
  __shared__ float Ms[DK * 32];
  const int sub = blockIdx.x;  // 0..7
  const int bh  = blockIdx.y;
  const int kh  = sub >> 2;    // k half
  const int vt  = sub & 3;     // v tile
  const int tid = threadIdx.x;
  const size_t mb = (size_t)bh * DK * DV;

  for (int i = tid; i < 64 * DK; i += 256)
    Gs[(i >> 7) * 129 + (i & 127)] = G[mb + (size_t)(kh * 64 + (i >> 7)) * DK + (i & 127)];
  for (int i = tid; i < DK * 32; i += 256)
    Ms[i] = Mg[mb + (size_t)(i >> 5) * DV + vt * 32 + (i & 31)];
  __syncthreads();

  const int kl = tid >> 2;
  const int vs = (tid & 3) * 8;
  float a[8];
#pragma unroll
  for (int j = 0; j < 8; ++j) a[j] = 0.f;
  for (int kk = 0; kk < DK; ++kk) {
    const float g = Gs[kl * 129 + kk];
#pragma unroll
    for (int j = 0; j < 8; ++j) a[j] += g * Ms[kk * 32 + vs + j];
  }
  float* dst = &newM[mb + (size_t)(kh * 64 + kl) * DV + vt * 32 + vs];
#pragma unroll
  for (int j = 0; j < 8; ++j) dst[j] -= a[j];
}

extern "C" void kernel_launch(void* const* d_in, const int* in_sizes, int n_in,
                              void* d_out, int out_size, void* d_ws, size_t ws_size,
                              hipStream_t stream) {
  const float* Kg = (const float*)d_in[0];
  const float* Vg = (const float*)d_in[1];
  const float* Mg = (const float*)d_in[2];
  const float* zg = (const float*)d_in[3];
  float* out  = (float*)d_out;
  float* newM = out;                              // BH*DK*DV floats
  float* newZ = out + (size_t)BH * DK * DV;       // BH*DK floats

  const size_t gredF = (size_t)BH * DK * DK;      // 1M floats (4 MB)
  const size_t need8 = ((size_t)BH * 8 * 32768 + gredF) * sizeof(float);  // ~71 MB

  hipMemcpyAsync(newZ, zg, sizeof(float) * (size_t)BH * DK,
                 hipMemcpyDeviceToDevice, stream);

  if (ws_size >= need8) {
    float* Pp   = (float*)d_ws;
    float* Gred = Pp + (size_t)BH * 8 * 32768;
    delta_phase1<8, true><<<dim3(8, BH), 512, 0, stream>>>(Kg, Vg, Pp, nullptr, newZ);
    delta_reduce<<<dim3(8, BH), 256, 0, stream>>>(Pp, Mg, newM, Gred, 8);
    delta_gm<<<dim3(8, BH), 256, 0, stream>>>(Mg, Gred, newM);
  } else {
    // Atomic fallback: newM/Gws pre-initialized, phase1 accumulates in place.
    float* Gws = (float*)d_ws;                    // 4 MB
    hipMemcpyAsync(newM, Mg, sizeof(float) * (size_t)BH * DK * DV,
                   hipMemcpyDeviceToDevice, stream);
    hipMemsetAsync(Gws, 0, sizeof(float) * gredF, stream);
    delta_phase1<8, false><<<dim3(8, BH), 512, 0, stream>>>(Kg, Vg, newM, Gws, newZ);
    delta_gm<<<dim3(8, BH), 256, 0, stream>>>(Mg, Gws, newM);
  }
}